// Round 1
// 287.782 us; speedup vs baseline: 1.0017x; 1.0017x over previous
//
#include <hip/hip_runtime.h>
#include <cstdint>
#include <cstddef>

// Problem constants
constexpr int B = 32, C = 256, H = 32, W = 32;
constexpr int NPTS = B * H * W;          // 32768 points
constexpr int DIM  = 256;                // embedding dim
constexpr int K    = 1024;               // codebook size
constexpr int QELEMS = B * C * H * W;    // 8388608 quantized elements
constexpr int CHW = C * H * W;           // 262144

typedef __attribute__((ext_vector_type(8))) short s8v;    // 8 bf16 (4 VGPRs)
typedef __attribute__((ext_vector_type(4))) float f32x4;  // MFMA acc

// Async global->LDS, 16B per lane. LDS dest is wave-uniform base + lane*16.
#define GLD_LDS16(g, l)                                                        \
  __builtin_amdgcn_global_load_lds(                                            \
      (const __attribute__((address_space(1))) unsigned int*)(g),              \
      (__attribute__((address_space(3))) unsigned int*)(l), 16, 0, 0)

__device__ __forceinline__ unsigned short f2bf(float f) {  // RNE fp32->bf16
  unsigned u = __float_as_uint(f);
  return (unsigned short)((u + 0x7FFFu + ((u >> 16) & 1u)) >> 16);
}

// ---------------- prep: eprep (blocks 0..15) + xprep (blocks 16..527) -------
// Unchanged from the 288us version (chains must stay bit-identical).
__global__ __launch_bounds__(256) void prep_kernel(
    const float* __restrict__ x, const float* __restrict__ emb,
    unsigned short* __restrict__ ehi, float* __restrict__ esq,
    unsigned short* __restrict__ xhi, float* __restrict__ xsq,
    float* __restrict__ loss) {
  __shared__ float xls[DIM][64];   // 64 KB; eprep uses first 1 KB as sums[4][64]
  const int t = threadIdx.x;

  if (blockIdx.x < 16) {
    if (blockIdx.x == 0 && t == 0) *loss = 0.f;
    float (*sums)[64] = (float (*)[64])xls;
    const int k = blockIdx.x * 64 + (t & 63);
    const int seg = t >> 6;                     // 4 segs x 64 c
    const float* er = emb + (size_t)k * DIM + seg * 64;
    float v[64];
    float4* v4 = (float4*)v;
#pragma unroll
    for (int i = 0; i < 16; ++i) v4[i] = *(const float4*)(er + i * 4);
    float s = 0.f;
#pragma unroll
    for (int i = 0; i < 64; ++i) s = fmaf(v[i], v[i], s);
    unsigned short* eo = ehi + (size_t)k * DIM + seg * 64;
#pragma unroll
    for (int i = 0; i < 8; ++i) {
      unsigned short h[8];
#pragma unroll
      for (int j = 0; j < 8; ++j) h[j] = f2bf(v[i * 8 + j]);
      *(s8v*)(eo + i * 8) = *(s8v*)h;
    }
    sums[seg][t & 63] = s;
    __syncthreads();
    if (t < 64)
      esq[blockIdx.x * 64 + t] =
          ((sums[0][t] + sums[1][t]) + sums[2][t]) + sums[3][t];
    return;
  }

  const int n0 = (blockIdx.x - 16) * 64;        // 512 x-blocks
  const int bb = n0 >> 10, hw0 = n0 & 1023;
  const int p = t & 63, cs = t >> 6;
  const float* xb = x + (size_t)bb * CHW + hw0;
#pragma unroll 8
  for (int r = 0; r < 64; ++r) {
    const int c = r * 4 + cs;
    xls[c][p] = xb[(size_t)c * 1024 + p];
  }
  __syncthreads();
  if (t < 64) {
    float s = 0.f;
#pragma unroll 8
    for (int c = 0; c < 256; ++c) {
      const float v = xls[c][t];
      s = fmaf(v, v, s);
    }
    xsq[n0 + t] = s;
  }
  const int p2 = t >> 2, cb = (t & 3) * 64;
  unsigned short* xo = xhi + (size_t)(n0 + p2) * DIM + cb;
#pragma unroll
  for (int i = 0; i < 8; ++i) {
    unsigned short h[8];
#pragma unroll
    for (int j = 0; j < 8; ++j) h[j] = f2bf(xls[cb + i * 8 + j][p2]);
    *(s8v*)(xo + i * 8) = *(s8v*)h;
  }
}

// ---------------- coarse argmin: bf16 MFMA + candidate emission -------------
// Block: 128n x 128k, 4 waves (2x2), wave tile 64x64 = 4x4 MFMA 16x16x32.
// grid = (NPTS/128, 8 k-splits). Margin M=1e-3 as before (argmin-safe).
// NEW: each of the 2048 blocks also zero-fills a 64 KB slice of enc (the
// one-hot zeros depend on nothing). Issued right after the MFMA K-loop so the
// stores drain under the fold/emission VALU work; finish only writes the 1s.
constexpr float MARGIN = 1e-3f;
__global__ __launch_bounds__(256) void coarse_kernel(
    const unsigned short* __restrict__ xhi, const unsigned short* __restrict__ ehi,
    const float* __restrict__ esq, const float* __restrict__ xsq,
    float* __restrict__ part, unsigned int* __restrict__ cand,
    float* __restrict__ encz) {
  __shared__ __align__(16) unsigned short xs[128][32];   // 8 KB
  __shared__ __align__(16) unsigned short es[128][32];   // 8 KB
  __shared__ float xsq_s[128], esq_s[128], thr_s[128];
  __shared__ unsigned long long red2[2][128];
  __shared__ unsigned int cntL[128];

  const int t = threadIdx.x;
  const int lane = t & 63, w = t >> 6;
  const int wn = (w & 1) * 64, wk = (w >> 1) * 64;
  const int col = lane & 15, quad = lane >> 4;
  const int nblk = blockIdx.x * 128;
  const int kblk = blockIdx.y * 128;

  if (t < 128) {
    xsq_s[t] = xsq[nblk + t];
    esq_s[t] = esq[kblk + t];
    cntL[t] = 0u;
  }

  f32x4 acc[4][4];
#pragma unroll
  for (int i = 0; i < 4; ++i)
#pragma unroll
    for (int j = 0; j < 4; ++j) acc[i][j] = (f32x4){0.f, 0.f, 0.f, 0.f};

  const int gl_row = lane >> 2;        // row within 16-row staging inst
  const int gl_c   = (lane & 3) * 8;   // bf16 col offset

  for (int c0 = 0; c0 < DIM; c0 += 32) {
    __syncthreads();   // previous tile fully consumed (drains lgkm+vm)
#pragma unroll
    for (int i = 0; i < 2; ++i) {
      const int inst = w + 4 * i;                 // wave-uniform
      const int row = inst * 16 + gl_row;
      GLD_LDS16(xhi + (size_t)(nblk + row) * DIM + c0 + gl_c, &xs[inst * 16][0]);
      GLD_LDS16(ehi + (size_t)(kblk + row) * DIM + c0 + gl_c, &es[inst * 16][0]);
    }
    __syncthreads();   // vmcnt(0): tiles visible
    s8v a[4], b[4];
#pragma unroll
    for (int ti = 0; ti < 4; ++ti)
      a[ti] = *(const s8v*)&xs[wn + ti * 16 + col][quad * 8];
#pragma unroll
    for (int tj = 0; tj < 4; ++tj)
      b[tj] = *(const s8v*)&es[wk + tj * 16 + col][quad * 8];
#pragma unroll
    for (int ti = 0; ti < 4; ++ti)
#pragma unroll
      for (int tj = 0; tj < 4; ++tj)
        acc[ti][tj] = __builtin_amdgcn_mfma_f32_16x16x32_bf16(
            a[ti], b[tj], acc[ti][tj], 0, 0, 0);
  }

  // ---- one-hot zero-fill slice (64 KB = 16384 floats per block) ----
  // encz float offset in out is 1+QELEMS === 1 (mod 4), so within a slice the
  // 16B-aligned float4 region starts at float 3. Covers floats 0..16383.
  {
    const size_t bidx = (size_t)blockIdx.y * gridDim.x + blockIdx.x;  // 0..2047
    float* sl = encz + bidx * 16384;
    float4* b4 = (float4*)(sl + 3);
    const float4 z4 = {0.f, 0.f, 0.f, 0.f};
#pragma unroll
    for (int j = 0; j < 16; ++j) {
      const int idx = t + j * 256;
      if (idx < 4095) b4[idx] = z4;
    }
    if (t == 0) { sl[0] = 0.f; sl[1] = 0.f; sl[2] = 0.f; sl[16383] = 0.f; }
  }

  // fold: per-thread per-n packed (d,k) min over its 4 k-tiles
  unsigned long long nmin[4][4];
#pragma unroll
  for (int ti = 0; ti < 4; ++ti)
#pragma unroll
    for (int r = 0; r < 4; ++r) nmin[ti][r] = ~0ULL;
#pragma unroll
  for (int ti = 0; ti < 4; ++ti)
#pragma unroll
    for (int tj = 0; tj < 4; ++tj) {
      const int krel = wk + tj * 16 + col;
      const float eq = esq_s[krel];
#pragma unroll
      for (int r = 0; r < 4; ++r) {
        const int nl = wn + ti * 16 + quad * 4 + r;
        const float d = (xsq_s[nl] + eq) - 2.f * acc[ti][tj][r];
        const unsigned long long key =
            ((unsigned long long)__float_as_uint(d) << 32) |
            (unsigned)(kblk + krel);
        if (key < nmin[ti][r]) nmin[ti][r] = key;   // d>0 -> uint-monotone
      }
    }
  // butterfly over the 16 cols (stays within quad)
#pragma unroll
  for (int o = 1; o < 16; o <<= 1)
#pragma unroll
    for (int ti = 0; ti < 4; ++ti)
#pragma unroll
      for (int r = 0; r < 4; ++r) {
        const unsigned long long v = __shfl_xor(nmin[ti][r], o, 64);
        if (v < nmin[ti][r]) nmin[ti][r] = v;
      }
  if (col == 0) {
#pragma unroll
    for (int ti = 0; ti < 4; ++ti)
#pragma unroll
      for (int r = 0; r < 4; ++r)
        red2[w >> 1][wn + ti * 16 + quad * 4 + r] = nmin[ti][r];
  }
  __syncthreads();
  if (t < 128) {
    const unsigned long long m0 = red2[0][t], m1 = red2[1][t];
    const unsigned long long m = (m1 < m0) ? m1 : m0;
    const float dmin = __uint_as_float((unsigned)(m >> 32));
    part[(size_t)(nblk + t) * 8 + blockIdx.y] = dmin;   // split-min
    thr_s[t] = dmin + MARGIN;
  }
  __syncthreads();
  // emission: all k with coarse d <= split_min + M
#pragma unroll
  for (int ti = 0; ti < 4; ++ti)
#pragma unroll
    for (int tj = 0; tj < 4; ++tj) {
      const int krel = wk + tj * 16 + col;
      const float eq = esq_s[krel];
#pragma unroll
      for (int r = 0; r < 4; ++r) {
        const int nl = wn + ti * 16 + quad * 4 + r;
        const float d = (xsq_s[nl] + eq) - 2.f * acc[ti][tj][r];
        if (d <= thr_s[nl]) {
          const unsigned slot = atomicAdd(&cntL[nl], 1u);
          if (slot < 4u)
            cand[((size_t)(nblk + nl) * 8 + blockIdx.y) * 4 + slot] =
                (unsigned)(kblk + krel);
        }
      }
    }
  __syncthreads();
  if (t < 128) {
    unsigned c = cntL[t];
    const size_t base = ((size_t)(nblk + t) * 8 + blockIdx.y) * 4;
    if (c > 4u) { cand[base + 3] = 0xFFFFFFFEu; c = 3u; }  // overflow -> rescan
    for (unsigned s = c; s < 4u; ++s) cand[base + s] = 0xFFFFFFFFu;
  }
}

// ------- finish: exact resolve + quantized write + ones + loss --------------
// RESTRUCTURED: 16 points/block, 2048 blocks. LDS ~19.8 KB -> 8 blocks/CU
// (was 3 at 53.9 KB). No enc zero phase (coarse wrote the zeros); the single
// 1.0f per point is a scalar store after ids are known (stream order makes
// the zero->one overwrite safe). No LDS tile: gather emb rows directly and
// fuse the loss. Phase-1 score chain (fmaf order, rescan path) is verbatim
// from the 288us version -> identical argmin.
__global__ __launch_bounds__(256) void finish_kernel(
    const float* __restrict__ x, const float* __restrict__ emb,
    const float* __restrict__ esq, const float* __restrict__ xsq,
    const float* __restrict__ part, const unsigned int* __restrict__ cand,
    float* __restrict__ outq, float* __restrict__ enc,
    float* __restrict__ loss) {
  __shared__ __align__(16) float xls[DIM][17];   // +1 pad: kills 4-way alias in gather
  __shared__ unsigned list[512];                 // bound: 16*8*4 = 512
  __shared__ unsigned long long best[16];
  __shared__ float thr_s[16];
  __shared__ float xsq_s[16];
  __shared__ float lred[4];
  __shared__ int ids[16];
  __shared__ int lcnt;

  const int t = threadIdx.x;
  const int n0 = blockIdx.x * 16;
  const int bb = n0 >> 10, hw0 = n0 & 1023;

  // ---- stage x tile once (64B segments, each line read exactly once) ----
  const float* xb = x + (size_t)bb * CHW + hw0;
  {
    const int p = t & 15, cs = t >> 4;   // 16 segs x 16 c
#pragma unroll 4
    for (int r = 0; r < 16; ++r) {
      const int c = r * 16 + cs;
      xls[c][p] = xb[(size_t)c * 1024 + p];
    }
  }
  if (t == 0) lcnt = 0;
  if (t < 16) {
    best[t] = ~0ULL;
    xsq_s[t] = xsq[n0 + t];
    const float4 p0 = *(const float4*)&part[(size_t)(n0 + t) * 8];
    const float4 p1 = *(const float4*)&part[(size_t)(n0 + t) * 8 + 4];
    float g = fminf(fminf(fminf(p0.x, p0.y), fminf(p0.z, p0.w)),
                    fminf(fminf(p1.x, p1.y), fminf(p1.z, p1.w)));
    thr_s[t] = g + MARGIN;
  }
  __syncthreads();

  // ---- build worklist: thread t<128 -> (point nn = t>>3, split s = t&7) ----
  if (t < 128) {
    const int nn = t >> 3, s = t & 7;
    const float pv = part[(size_t)(n0 + nn) * 8 + s];
    if (pv <= thr_s[nn]) {
      const uint4 c4 = *(const uint4*)&cand[((size_t)(n0 + nn) * 8 + s) * 4];
      const unsigned vs[4] = {c4.x, c4.y, c4.z, c4.w};
#pragma unroll
      for (int i = 0; i < 4; ++i) {
        const unsigned v = vs[i];
        if (v == 0xFFFFFFFFu) continue;
        const unsigned entry = (v == 0xFFFFFFFEu)
                                   ? ((unsigned)nn << 11) | 1024u | (unsigned)s
                                   : ((unsigned)nn << 11) | (v & 1023u);
        const int pos = atomicAdd(&lcnt, 1);
        if (pos < 512) list[pos] = entry;
      }
    }
  }
  __syncthreads();

  // ---- consume worklist; score chain verbatim (bit-identical argmin) ----
  const int L = lcnt < 512 ? lcnt : 512;
  for (int e = t; e < L; e += 256) {
    const unsigned entry = list[e];
    const int p = entry >> 11;
    const float xq = xsq_s[p];
    int klo, khi;
    if (entry & 1024u) { const int s = entry & 7; klo = s * 128; khi = klo + 128; }
    else               { klo = entry & 1023u; khi = klo + 1; }
    for (int k = klo; k < khi; ++k) {
      const float* er = emb + (size_t)k * DIM;
      float dot = 0.f;
#pragma unroll 4
      for (int c4 = 0; c4 < DIM; c4 += 4) {
        const float4 e4 = *(const float4*)(er + c4);
        dot = fmaf(xls[c4 + 0][p], e4.x, dot);
        dot = fmaf(xls[c4 + 1][p], e4.y, dot);
        dot = fmaf(xls[c4 + 2][p], e4.z, dot);
        dot = fmaf(xls[c4 + 3][p], e4.w, dot);
      }
      const float t1 = xq + esq[k];
      const float d = t1 - 2.f * dot;
      const unsigned long long key =
          ((unsigned long long)__float_as_uint(d) << 32) | (unsigned)k;
      atomicMin(&best[p], key);   // d>0 -> uint-monotone; low k wins ties
    }
  }
  __syncthreads();
  if (t < 16) ids[t] = (int)(best[t] & 0xFFFFFFFFu);
  __syncthreads();

  // ---- direct gather + quantized write + fused loss ----
  // thread (p = t&15, g = t>>4): reads emb[id_p][g*16..g*16+15] (distinct
  // 64B chunk per thread, emb is L2-resident), writes 16 scalars to outq
  // (4 x 64B segments per wave instr) and accumulates (q-x)^2.
  float lsum = 0.f;
  {
    const int p = t & 15, g = t >> 4;
    const int row = ids[p];
    const float* er = emb + (size_t)row * DIM + g * 16;
    float* ob = outq + (size_t)bb * CHW + hw0 + p;
#pragma unroll
    for (int i = 0; i < 4; ++i) {
      const float4 v = *(const float4*)(er + i * 4);
      const int c = g * 16 + i * 4;
      float d0 = v.x - xls[c + 0][p];
      float d1 = v.y - xls[c + 1][p];
      float d2 = v.z - xls[c + 2][p];
      float d3 = v.w - xls[c + 3][p];
      ob[(size_t)(c + 0) * 1024] = v.x;
      ob[(size_t)(c + 1) * 1024] = v.y;
      ob[(size_t)(c + 2) * 1024] = v.z;
      ob[(size_t)(c + 3) * 1024] = v.w;
      lsum = fmaf(d0, d0, lsum);
      lsum = fmaf(d1, d1, lsum);
      lsum = fmaf(d2, d2, lsum);
      lsum = fmaf(d3, d3, lsum);
    }
  }

  // ---- one-hot: single 1.0f per point (zeros already written by coarse) ----
  if (t < 16) enc[(size_t)(n0 + t) * K + ids[t]] = 1.0f;

  // ---- loss reduction ----
  float s = lsum;
#pragma unroll
  for (int o = 32; o > 0; o >>= 1) s += __shfl_down(s, o, 64);
  if ((t & 63) == 0) lred[t >> 6] = s;
  __syncthreads();
  if (t == 0) {
    const float tot = (((lred[0] + lred[1]) + lred[2]) + lred[3]) *
                      (1.25f / (float)QELEMS);
    atomicAdd(loss, tot);   // loss = q_latent + 0.25*e_latent = 1.25 * MSE
  }
}

extern "C" void kernel_launch(void* const* d_in, const int* in_sizes, int n_in,
                              void* d_out, int out_size, void* d_ws, size_t ws_size,
                              hipStream_t stream) {
  const float* x   = (const float*)d_in[0];
  const float* emb = (const float*)d_in[1];
  float* out  = (float*)d_out;
  float* loss = out;                       // [1]
  float* outq = out + 1;                   // [8388608], 4B-aligned only
  float* enc  = out + 1 + QELEMS;          // [33554432], 4B-aligned only

  char* ws = (char*)d_ws;
  unsigned short* ehi  = (unsigned short*)ws;                  // 512 KB
  float*          esq  = (float*)(ws + 524288);                // 4 KB
  float*          xsq  = (float*)(ws + 528384);                // 128 KB
  float*          part = (float*)(ws + 659456);                // 1 MB
  unsigned int*   cand = (unsigned int*)(ws + 1708032);        // 4 MB
  unsigned short* xhi  = (unsigned short*)(ws + 5902336);      // 16 MB
  // total ws use: ~22.7 MB

  prep_kernel<<<16 + NPTS / 64, 256, 0, stream>>>(x, emb, ehi, esq, xhi, xsq,
                                                  loss);
  dim3 cg(NPTS / 128, 8);
  coarse_kernel<<<cg, 256, 0, stream>>>(xhi, ehi, esq, xsq, part, cand, enc);
  finish_kernel<<<NPTS / 16, 256, 0, stream>>>(x, emb, esq, xsq, part, cand,
                                               outq, enc, loss);
}